// Round 5
// baseline (82.680 us; speedup 1.0000x reference)
//
#include <hip/hip_runtime.h>
#include <math.h>

#define NTOK 784
#define DIM 128
#define FFD 512

// ================= K1: posw (169 blocks) || LN1+qkv (78 blocks) =================
__global__ __launch_bounds__(256) void posw_qkv(
    const float* __restrict__ pu, const float* __restrict__ pv, float* __restrict__ W,
    const float* __restrict__ x, const float* __restrict__ g, const float* __restrict__ b,
    const float* __restrict__ wq, const float* __restrict__ wk, const float* __restrict__ wv,
    float* __restrict__ q, float* __restrict__ ek, float* __restrict__ vv) {
  __shared__ float smem[16896];  // 66 KB, role-dependent layout
  int tid = threadIdx.x;

  if (blockIdx.x < 169) {
    float (*As)[64] = (float(*)[64])smem;
    float (*Bs)[64] = (float(*)[64])(smem + 2048);
    int pb = blockIdx.x;
    int m0 = (pb % 13) * 64, n0 = (pb / 13) * 64;
    int tx = tid & 15, ty = tid >> 4;
    int r = tid >> 2, kq = (tid & 3) * 8;
    int gm = m0 + r; if (gm > NTOK - 1) gm = NTOK - 1;
    int gn = n0 + r; if (gn > NTOK - 1) gn = NTOK - 1;
    float acc[4][4] = {};
    for (int kt = 0; kt < 4; ++kt) {
      int k0 = kt * 32;
#pragma unroll
      for (int j = 0; j < 8; ++j) As[kq + j][r] = pu[gm * DIM + k0 + kq + j];
#pragma unroll
      for (int j = 0; j < 8; ++j) Bs[kq + j][r] = pv[gn * DIM + k0 + kq + j];
      __syncthreads();
#pragma unroll
      for (int kk = 0; kk < 32; ++kk) {
        float4 a4 = *(const float4*)&As[kk][ty * 4];
        float4 b4 = *(const float4*)&Bs[kk][tx * 4];
        float av[4] = {a4.x, a4.y, a4.z, a4.w};
        float bv[4] = {b4.x, b4.y, b4.z, b4.w};
#pragma unroll
        for (int i = 0; i < 4; ++i)
#pragma unroll
          for (int j = 0; j < 4; ++j) acc[i][j] = fmaf(av[i], bv[j], acc[i][j]);
      }
      __syncthreads();
    }
    int c0 = n0 + tx * 4;
    if (c0 + 3 < NTOK) {
#pragma unroll
      for (int i = 0; i < 4; ++i) {
        int gr = m0 + ty * 4 + i;
        if (gr < NTOK) {
          float4 o = {expf(acc[i][0]), expf(acc[i][1]), expf(acc[i][2]), expf(acc[i][3])};
          *(float4*)&W[gr * NTOK + c0] = o;
        }
      }
    }
  } else {
    float (*Xs)[64] = (float(*)[64])smem;
    float (*Bs)[64] = (float(*)[64])(smem + 8192);
    float (*redS)[64] = (float(*)[64])(smem + 16384);
    float (*redQ)[64] = (float(*)[64])(smem + 16640);
    int bid = blockIdx.x - 169;
    int m0 = (bid % 13) * 64;
    int ct = bid / 13;
    int wsel = ct >> 1;
    int n0 = (ct & 1) * 64;
    const float* B = (wsel == 0) ? wq : (wsel == 1) ? wk : wv;

    if (m0 + 64 <= NTOK) {
#pragma unroll
      for (int it = 0; it < 8; ++it) {
        int idx = it * 256 + tid;
        int c = idx >> 4, j4 = (idx & 15) * 4;
        float4 v = *(const float4*)&x[c * NTOK + m0 + j4];
        Xs[c][j4 + 0] = v.x; Xs[c][j4 + 1] = v.y; Xs[c][j4 + 2] = v.z; Xs[c][j4 + 3] = v.w;
      }
    } else {
#pragma unroll
      for (int it = 0; it < 8; ++it) {
        int idx = it * 256 + tid;
        int c = idx >> 4, j4 = (idx & 15) * 4;
#pragma unroll
        for (int u = 0; u < 4; ++u) {
          int n = m0 + j4 + u; if (n > NTOK - 1) n = NTOK - 1;
          Xs[c][j4 + u] = x[c * NTOK + n];
        }
      }
    }
    __syncthreads();

    int n = tid & 63, grp = tid >> 6;
    float s = 0.f, ss = 0.f;
    for (int c = grp * 32; c < grp * 32 + 32; ++c) { float v = Xs[c][n]; s += v; ss += v * v; }
    redS[grp][n] = s; redQ[grp][n] = ss;
    __syncthreads();
    float sum = redS[0][n] + redS[1][n] + redS[2][n] + redS[3][n];
    float sq  = redQ[0][n] + redQ[1][n] + redQ[2][n] + redQ[3][n];
    float mu = sum * (1.0f / DIM);
    float var = sq * (1.0f / DIM) - mu * mu;
    float rs = rsqrtf(var + 1e-5f);
    for (int c = grp * 32; c < grp * 32 + 32; ++c)
      Xs[c][n] = (Xs[c][n] - mu) * rs * g[c] + b[c];

    int r = tid >> 2, kc = tid & 3;
#pragma unroll
    for (int j = 0; j < 8; ++j) {
      int k = kc * 32 + j * 4;
      float4 v = *(const float4*)&B[(n0 + r) * DIM + k];
      Bs[k + 0][r] = v.x; Bs[k + 1][r] = v.y; Bs[k + 2][r] = v.z; Bs[k + 3][r] = v.w;
    }
    __syncthreads();

    int tx = tid & 15, ty = tid >> 4;
    float acc[4][4] = {};
#pragma unroll 4
    for (int kk = 0; kk < DIM; ++kk) {
      float4 a4 = *(const float4*)&Xs[kk][ty * 4];
      float4 b4 = *(const float4*)&Bs[kk][tx * 4];
      float av[4] = {a4.x, a4.y, a4.z, a4.w};
      float bv[4] = {b4.x, b4.y, b4.z, b4.w};
#pragma unroll
      for (int i = 0; i < 4; ++i)
#pragma unroll
        for (int j = 0; j < 4; ++j) acc[i][j] = fmaf(av[i], bv[j], acc[i][j]);
    }
    int c0 = n0 + tx * 4;
    float* dst = (wsel == 0) ? q : (wsel == 1) ? ek : vv;
#pragma unroll
    for (int i = 0; i < 4; ++i) {
      int gr = m0 + ty * 4 + i;
      if (gr < NTOK) {
        float4 o;
        if (wsel == 0) {
          o.x = 1.0f / (1.0f + expf(-acc[i][0]));
          o.y = 1.0f / (1.0f + expf(-acc[i][1]));
          o.z = 1.0f / (1.0f + expf(-acc[i][2]));
          o.w = 1.0f / (1.0f + expf(-acc[i][3]));
        } else if (wsel == 1) {
          o.x = expf(acc[i][0]); o.y = expf(acc[i][1]);
          o.z = expf(acc[i][2]); o.w = expf(acc[i][3]);
        } else {
          o.x = acc[i][0]; o.y = acc[i][1]; o.z = acc[i][2]; o.w = acc[i][3];
        }
        *(float4*)&dst[gr * DIM + c0] = o;
      }
    }
  }
}

// ================= K2: agg, K-split 8, grid (13,2,8), 512 thr =================
__global__ __launch_bounds__(512) void agg_gemm(
    const float* __restrict__ W, const float* __restrict__ ek,
    const float* __restrict__ vv, float* __restrict__ nump, float* __restrict__ denp) {
  __shared__ float As[32][64];
  __shared__ float Bn[32][64];
  __shared__ float Bd[32][64];
  int tid = threadIdx.x;
  int m0 = blockIdx.x * 64, d0 = blockIdx.y * 64, s = blockIdx.z;
  int tx = tid & 15, ty = tid >> 4;
  int ra = tid >> 3, ka = (tid & 7) * 4;
  int kb = tid >> 4, db = (tid & 15) * 4;
  int gm = m0 + ra; if (gm > NTOK - 1) gm = NTOK - 1;
  float an[2][4] = {}, ad[2][4] = {};
  int ktlo = (s * 25) / 8, kthi = ((s + 1) * 25) / 8;
  for (int kt = ktlo; kt < kthi; ++kt) {
    int k0 = kt * 32;
    if (k0 + 32 <= NTOK) {
      float4 a = *(const float4*)&W[gm * NTOK + k0 + ka];
      As[ka + 0][ra] = a.x; As[ka + 1][ra] = a.y;
      As[ka + 2][ra] = a.z; As[ka + 3][ra] = a.w;
      int gk = k0 + kb;
      float4 e = *(const float4*)&ek[gk * DIM + d0 + db];
      float4 w = *(const float4*)&vv[gk * DIM + d0 + db];
      Bd[kb][db + 0] = e.x; Bd[kb][db + 1] = e.y; Bd[kb][db + 2] = e.z; Bd[kb][db + 3] = e.w;
      Bn[kb][db + 0] = e.x * w.x; Bn[kb][db + 1] = e.y * w.y;
      Bn[kb][db + 2] = e.z * w.z; Bn[kb][db + 3] = e.w * w.w;
    } else {
#pragma unroll
      for (int j = 0; j < 4; ++j) {
        int gk = k0 + ka + j;
        As[ka + j][ra] = (gk < NTOK) ? W[gm * NTOK + gk] : 0.f;
      }
      int gk = k0 + kb;
      if (gk < NTOK) {
        float4 e = *(const float4*)&ek[gk * DIM + d0 + db];
        float4 w = *(const float4*)&vv[gk * DIM + d0 + db];
        Bd[kb][db + 0] = e.x; Bd[kb][db + 1] = e.y; Bd[kb][db + 2] = e.z; Bd[kb][db + 3] = e.w;
        Bn[kb][db + 0] = e.x * w.x; Bn[kb][db + 1] = e.y * w.y;
        Bn[kb][db + 2] = e.z * w.z; Bn[kb][db + 3] = e.w * w.w;
      } else {
        Bd[kb][db + 0] = 0.f; Bd[kb][db + 1] = 0.f; Bd[kb][db + 2] = 0.f; Bd[kb][db + 3] = 0.f;
        Bn[kb][db + 0] = 0.f; Bn[kb][db + 1] = 0.f; Bn[kb][db + 2] = 0.f; Bn[kb][db + 3] = 0.f;
      }
    }
    __syncthreads();
#pragma unroll
    for (int kk = 0; kk < 32; ++kk) {
      float2 a2 = *(const float2*)&As[kk][ty * 2];
      float4 n4 = *(const float4*)&Bn[kk][tx * 4];
      float4 d4 = *(const float4*)&Bd[kk][tx * 4];
      float av[2] = {a2.x, a2.y};
      float nv[4] = {n4.x, n4.y, n4.z, n4.w};
      float dv[4] = {d4.x, d4.y, d4.z, d4.w};
#pragma unroll
      for (int i = 0; i < 2; ++i)
#pragma unroll
        for (int j = 0; j < 4; ++j) {
          an[i][j] = fmaf(av[i], nv[j], an[i][j]);
          ad[i][j] = fmaf(av[i], dv[j], ad[i][j]);
        }
    }
    __syncthreads();
  }
#pragma unroll
  for (int i = 0; i < 2; ++i) {
    int gr = m0 + ty * 2 + i;
    if (gr < NTOK) {
      float4 on = {an[i][0], an[i][1], an[i][2], an[i][3]};
      float4 od = {ad[i][0], ad[i][1], ad[i][2], ad[i][3]};
      *(float4*)&nump[(s * NTOK + gr) * DIM + d0 + tx * 4] = on;
      *(float4*)&denp[(s * NTOK + gr) * DIM + d0 + tx * 4] = od;
    }
  }
}

// ---------- K3: fused gate + O-proj + residual + LN2, grid 49, 512 thr ----------
__global__ __launch_bounds__(512) void proj_gate_ln(
    const float* __restrict__ q, const float* __restrict__ nump,
    const float* __restrict__ denp, const float* __restrict__ wo,
    const float* __restrict__ bo, const float* __restrict__ x,
    const float* __restrict__ g2, const float* __restrict__ b2n,
    float* __restrict__ t2, float* __restrict__ fn) {
  __shared__ float At[DIM][17];    // attn tile, k-major [c][n], padded
  __shared__ float Bs[DIM][DIM];   // wo, k-major [k][c]
  int tid = threadIdx.x;
  int m0 = blockIdx.x * 16;        // 49*16 = 784 exact

  // stage attn tile: attn[n][c] = q * sum(num)/sum(den)  (8 partials)
  {
    int nn = tid >> 5, c4 = (tid & 31) * 4;
    int base = (m0 + nn) * DIM + c4;
    float4 qv = *(const float4*)&q[base];
    float4 nv = {0.f, 0.f, 0.f, 0.f}, dv = {0.f, 0.f, 0.f, 0.f};
#pragma unroll
    for (int s = 0; s < 8; ++s) {
      float4 a = *(const float4*)&nump[s * NTOK * DIM + base];
      float4 d = *(const float4*)&denp[s * NTOK * DIM + base];
      nv.x += a.x; nv.y += a.y; nv.z += a.z; nv.w += a.w;
      dv.x += d.x; dv.y += d.y; dv.z += d.z; dv.w += d.w;
    }
    At[c4 + 0][nn] = qv.x * (nv.x / dv.x);
    At[c4 + 1][nn] = qv.y * (nv.y / dv.y);
    At[c4 + 2][nn] = qv.z * (nv.z / dv.z);
    At[c4 + 3][nn] = qv.w * (nv.w / dv.w);
  }
  // stage full wo (k-major)
  {
    int r = tid >> 2, kc = tid & 3;
#pragma unroll
    for (int j = 0; j < 8; ++j) {
      int k = kc * 32 + j * 4;
      float4 v = *(const float4*)&wo[r * DIM + k];
      Bs[k + 0][r] = v.x; Bs[k + 1][r] = v.y; Bs[k + 2][r] = v.z; Bs[k + 3][r] = v.w;
    }
  }
  __syncthreads();

  int ty = tid >> 5, tx = tid & 31;   // 1 row x 4 cols per thread
  float acc[4] = {0.f, 0.f, 0.f, 0.f};
#pragma unroll 4
  for (int kk = 0; kk < DIM; ++kk) {
    float a = At[kk][ty];
    float4 b4 = *(const float4*)&Bs[kk][tx * 4];
    acc[0] = fmaf(a, b4.x, acc[0]);
    acc[1] = fmaf(a, b4.y, acc[1]);
    acc[2] = fmaf(a, b4.z, acc[2]);
    acc[3] = fmaf(a, b4.w, acc[3]);
  }
  int gn = m0 + ty;
  int c0 = tx * 4;
  float4 bias = *(const float4*)&bo[c0];
  float4 o;
  o.x = acc[0] + bias.x + x[(c0 + 0) * NTOK + gn];
  o.y = acc[1] + bias.y + x[(c0 + 1) * NTOK + gn];
  o.z = acc[2] + bias.z + x[(c0 + 2) * NTOK + gn];
  o.w = acc[3] + bias.w + x[(c0 + 3) * NTOK + gn];
  *(float4*)&t2[gn * DIM + c0] = o;

  // LN2 in registers: 32 lanes per row
  float s = o.x + o.y + o.z + o.w;
  float ss = o.x * o.x + o.y * o.y + o.z * o.z + o.w * o.w;
#pragma unroll
  for (int off = 1; off < 32; off <<= 1) {
    s += __shfl_xor(s, off);
    ss += __shfl_xor(ss, off);
  }
  float mu = s * (1.0f / DIM);
  float var = ss * (1.0f / DIM) - mu * mu;
  float rs = rsqrtf(var + 1e-5f);
  float4 gg = *(const float4*)&g2[c0];
  float4 bb = *(const float4*)&b2n[c0];
  float4 f;
  f.x = (o.x - mu) * rs * gg.x + bb.x;
  f.y = (o.y - mu) * rs * gg.y + bb.y;
  f.z = (o.z - mu) * rs * gg.z + bb.z;
  f.w = (o.w - mu) * rs * gg.w + bb.w;
  *(float4*)&fn[gn * DIM + c0] = f;
}

// ---------- K4: ff1 = gelu(fn @ w1^T + b1), grid (13,8), 256 thr ----------
__global__ __launch_bounds__(256) void ff1_gemm(
    const float* __restrict__ fn, const float* __restrict__ w1,
    const float* __restrict__ b1, float* __restrict__ ff1) {
  __shared__ float As[32][64];
  __shared__ float Bs[32][64];
  int tid = threadIdx.x;
  int m0 = blockIdx.x * 64, n0 = blockIdx.y * 64;
  int tx = tid & 15, ty = tid >> 4;
  int r = tid >> 2, kq = (tid & 3) * 8;
  int gm = m0 + r; if (gm > NTOK - 1) gm = NTOK - 1;
  float acc[4][4] = {};
  for (int kt = 0; kt < 4; ++kt) {
    int k0 = kt * 32;
#pragma unroll
    for (int j = 0; j < 8; ++j) As[kq + j][r] = fn[gm * DIM + k0 + kq + j];
#pragma unroll
    for (int j = 0; j < 8; ++j) Bs[kq + j][r] = w1[(n0 + r) * DIM + k0 + kq + j];
    __syncthreads();
#pragma unroll
    for (int kk = 0; kk < 32; ++kk) {
      float4 a4 = *(const float4*)&As[kk][ty * 4];
      float4 b4 = *(const float4*)&Bs[kk][tx * 4];
      float av[4] = {a4.x, a4.y, a4.z, a4.w};
      float bv[4] = {b4.x, b4.y, b4.z, b4.w};
#pragma unroll
      for (int i = 0; i < 4; ++i)
#pragma unroll
        for (int j = 0; j < 4; ++j) acc[i][j] = fmaf(av[i], bv[j], acc[i][j]);
    }
    __syncthreads();
  }
  int c0 = n0 + tx * 4;
  float4 bias = *(const float4*)&b1[c0];
  float bb[4] = {bias.x, bias.y, bias.z, bias.w};
#pragma unroll
  for (int i = 0; i < 4; ++i) {
    int gr = m0 + ty * 4 + i;
    if (gr < NTOK) {
      float4 o;
      float* op = &o.x;
#pragma unroll
      for (int j = 0; j < 4; ++j) {
        float xv = acc[i][j] + bb[j];
        op[j] = 0.5f * xv * (1.0f + erff(xv * 0.70710678118654752f));
      }
      *(float4*)&ff1[gr * FFD + c0] = o;
    }
  }
}

// ---------- K5: ff2 + residual, transposed write, grid (13,2), 512 thr ----------
__global__ __launch_bounds__(512) void ff2_gemm(
    const float* __restrict__ ff1, const float* __restrict__ w2,
    const float* __restrict__ b2, const float* __restrict__ t2, float* __restrict__ out) {
  __shared__ float As[32][64];
  __shared__ float Bs[32][64];
  int tid = threadIdx.x;
  int m0 = blockIdx.x * 64, n0 = blockIdx.y * 64;
  int tx = tid & 15, ty = tid >> 4;
  int ra = tid >> 3, ka = (tid & 7) * 4;
  int gm = m0 + ra; if (gm > NTOK - 1) gm = NTOK - 1;
  float acc[2][4] = {};
  for (int kt = 0; kt < 16; ++kt) {
    int k0 = kt * 32;
    {
      float4 a = *(const float4*)&ff1[gm * FFD + k0 + ka];
      As[ka + 0][ra] = a.x; As[ka + 1][ra] = a.y;
      As[ka + 2][ra] = a.z; As[ka + 3][ra] = a.w;
      float4 bb = *(const float4*)&w2[(n0 + ra) * FFD + k0 + ka];
      Bs[ka + 0][ra] = bb.x; Bs[ka + 1][ra] = bb.y;
      Bs[ka + 2][ra] = bb.z; Bs[ka + 3][ra] = bb.w;
    }
    __syncthreads();
#pragma unroll
    for (int kk = 0; kk < 32; ++kk) {
      float2 a2 = *(const float2*)&As[kk][ty * 2];
      float4 b4 = *(const float4*)&Bs[kk][tx * 4];
      float av[2] = {a2.x, a2.y};
      float bv[4] = {b4.x, b4.y, b4.z, b4.w};
#pragma unroll
      for (int i = 0; i < 2; ++i)
#pragma unroll
        for (int j = 0; j < 4; ++j) acc[i][j] = fmaf(av[i], bv[j], acc[i][j]);
    }
    __syncthreads();
  }
  int c = n0 + tx * 4;
  float4 bias = *(const float4*)&b2[c];
#pragma unroll
  for (int i = 0; i < 2; ++i) {
    int gr = m0 + ty * 2 + i;
    if (gr < NTOK) {
      float4 t = *(const float4*)&t2[gr * DIM + c];
      out[(c + 0) * NTOK + gr] = acc[i][0] + bias.x + t.x;
      out[(c + 1) * NTOK + gr] = acc[i][1] + bias.y + t.y;
      out[(c + 2) * NTOK + gr] = acc[i][2] + bias.z + t.z;
      out[(c + 3) * NTOK + gr] = acc[i][3] + bias.w + t.w;
    }
  }
}

extern "C" void kernel_launch(void* const* d_in, const int* in_sizes, int n_in,
                              void* d_out, int out_size, void* d_ws, size_t ws_size,
                              hipStream_t stream) {
  const float* x   = (const float*)d_in[0];
  const float* wq  = (const float*)d_in[1];
  const float* wk  = (const float*)d_in[2];
  const float* wv  = (const float*)d_in[3];
  const float* wo  = (const float*)d_in[4];
  const float* bo  = (const float*)d_in[5];
  const float* pu  = (const float*)d_in[6];
  const float* pv  = (const float*)d_in[7];
  const float* g1  = (const float*)d_in[8];
  const float* b1n = (const float*)d_in[9];
  const float* g2  = (const float*)d_in[10];
  const float* b2n = (const float*)d_in[11];
  const float* w1  = (const float*)d_in[12];
  const float* b1f = (const float*)d_in[13];
  const float* w2  = (const float*)d_in[14];
  const float* b2f = (const float*)d_in[15];
  float* out = (float*)d_out;

  float* ws = (float*)d_ws;
  float* q    = ws;                 // [784,128]
  float* ek   = ws + 100352;        // [784,128]
  float* vv   = ws + 200704;        // [784,128]
  float* t2   = ws + 301056;        // [784,128]
  float* fn   = ws + 401408;        // [784,128]
  float* W    = ws + 501760;        // [784,784]; reused as ff1 [784,512]
  float* nump = ws + 1116416;       // [8,784,128]
  float* denp = ws + 1919232;       // [8,784,128]

  posw_qkv<<<247, 256, 0, stream>>>(pu, pv, W, x, g1, b1n, wq, wk, wv, q, ek, vv);
  agg_gemm<<<dim3(13, 2, 8), 512, 0, stream>>>(W, ek, vv, nump, denp);
  proj_gate_ln<<<49, 512, 0, stream>>>(q, nump, denp, wo, bo, x, g2, b2n, t2, fn);
  ff1_gemm<<<dim3(13, 8), 256, 0, stream>>>(fn, w1, b1f, W);   // W := ff1
  ff2_gemm<<<dim3(13, 2), 512, 0, stream>>>(W, w2, b2f, t2, out);
}